// Round 1
// baseline (71.536 us; speedup 1.0000x reference)
//
#include <hip/hip_runtime.h>
#include <math.h>

#define V_ROWS 20000
#define DIM    128
#define NPAIRS 65536

constexpr int COLSUM_BLOCKS = 128;   // partial column-sum blocks
constexpr int PAIR_BLOCKS   = 512;   // 512 blocks x 256 thr = 2048 waves

// ---------------- Kernel A: partial column sums of embedding ----------------
// block b sums rows [r0, r1) ; thread t owns column t. Coalesced: 128 threads
// read one contiguous 512B row per iteration.
__global__ void colsum_partial(const float* __restrict__ emb,
                               float* __restrict__ part) {
    const int t = threadIdx.x;            // 0..127
    const int b = blockIdx.x;
    const int rows_per = (V_ROWS + gridDim.x - 1) / gridDim.x;
    const int r0 = b * rows_per;
    const int r1 = min(r0 + rows_per, V_ROWS);
    float s = 0.f;
    for (int r = r0; r < r1; ++r) s += emb[(size_t)r * DIM + t];
    part[b * DIM + t] = s;
}

// ---------------- Kernel B: reduce partials -> S[128] ----------------
__global__ void colsum_reduce(const float* __restrict__ part,
                              float* __restrict__ S) {
    const int t = threadIdx.x;            // 0..127
    float s = 0.f;
    for (int b = 0; b < COLSUM_BLOCKS; ++b) s += part[b * DIM + t];
    S[t] = s;
}

// ---------------- Kernel C: per-pair cost, per-block partial sums -----------
// One wave (64 lanes) per pair (grid-strided). Lane l holds dims {2l, 2l+1}
// as float2. Butterfly shfl_xor reduces dot products across the wave.
__global__ void pair_kernel(const float* __restrict__ emb,
                            const int* __restrict__ iv,
                            const int* __restrict__ jv,
                            const float* __restrict__ S,
                            float* __restrict__ blockpart) {
    const int lane = threadIdx.x & 63;
    const int wid  = threadIdx.x >> 6;
    const int wavesPerBlock = blockDim.x >> 6;
    const int gw = blockIdx.x * wavesPerBlock + wid;
    const int nw = gridDim.x * wavesPerBlock;

    // S is constant across pairs: load this lane's 2 elements once.
    const float2 sv = reinterpret_cast<const float2*>(S)[lane];

    float acc = 0.f;
    for (int p = gw; p < NPAIRS; p += nw) {
        const int i = iv[p];
        const int j = jv[p];
        const float2 ei = reinterpret_cast<const float2*>(emb + (size_t)i * DIM)[lane];
        const float2 ej = reinterpret_cast<const float2*>(emb + (size_t)j * DIM)[lane];
        float d = ei.x * ej.x + ei.y * ej.y;   // e_i . e_j  (partial)
        float n = ei.x * sv.x + ei.y * sv.y;   // e_i . S    (partial)
        #pragma unroll
        for (int off = 32; off > 0; off >>= 1) {
            d += __shfl_xor(d, off);
            n += __shfl_xor(n, off);
        }
        // all lanes now hold the full dots; compute on all lanes (uniform)
        const float cost = -logf(expf(d - n) + 1e-8f);
        if (lane == 0) acc += cost;
    }

    __shared__ float ls[8];
    if (lane == 0) ls[wid] = acc;
    __syncthreads();
    if (threadIdx.x == 0) {
        float s = 0.f;
        for (int w = 0; w < wavesPerBlock; ++w) s += ls[w];
        blockpart[blockIdx.x] = s;
    }
}

// ---------------- Kernel D: final reduce -> mean ----------------
__global__ void final_reduce(const float* __restrict__ blockpart,
                             float* __restrict__ out) {
    const int t = threadIdx.x;            // 256 threads
    float s = 0.f;
    for (int idx = t; idx < PAIR_BLOCKS; idx += blockDim.x) s += blockpart[idx];
    // wave butterfly
    #pragma unroll
    for (int off = 32; off > 0; off >>= 1) s += __shfl_xor(s, off);
    __shared__ float ls[4];
    if ((t & 63) == 0) ls[t >> 6] = s;
    __syncthreads();
    if (t == 0) {
        float tot = ls[0] + ls[1] + ls[2] + ls[3];
        out[0] = tot / (float)NPAIRS;
    }
}

extern "C" void kernel_launch(void* const* d_in, const int* in_sizes, int n_in,
                              void* d_out, int out_size, void* d_ws, size_t ws_size,
                              hipStream_t stream) {
    const float* emb = (const float*)d_in[0];
    const int*   iv  = (const int*)d_in[1];
    const int*   jv  = (const int*)d_in[2];
    float* out = (float*)d_out;

    float* ws    = (float*)d_ws;
    float* part  = ws;                              // COLSUM_BLOCKS*128 floats
    float* S     = part + COLSUM_BLOCKS * DIM;      // 128 floats
    float* bpart = S + DIM;                         // PAIR_BLOCKS floats

    hipLaunchKernelGGL(colsum_partial, dim3(COLSUM_BLOCKS), dim3(DIM), 0, stream,
                       emb, part);
    hipLaunchKernelGGL(colsum_reduce, dim3(1), dim3(DIM), 0, stream,
                       part, S);
    hipLaunchKernelGGL(pair_kernel, dim3(PAIR_BLOCKS), dim3(256), 0, stream,
                       emb, iv, jv, S, bpart);
    hipLaunchKernelGGL(final_reduce, dim3(1), dim3(256), 0, stream,
                       bpart, out);
}

// Round 2
// 58.322 us; speedup vs baseline: 1.2266x; 1.2266x over previous
//
#include <hip/hip_runtime.h>
#include <math.h>

#define V_ROWS 20000
#define DIM    128
#define NPAIRS 65536
#define NFLOAT4 (V_ROWS * DIM / 4)   // 640000

constexpr int CS_BLOCKS  = 512;
constexpr int CS_THREADS = 256;
constexpr int PAIR_BLOCKS = 512;

// ---------------- Kernel A: partial column sums, float4 grid-stride ---------
// stride*4 % 128 == 0, so each thread's 4 columns are fixed: (tid*4) & 127.
__global__ void colsum_partial(const float4* __restrict__ emb4,
                               float* __restrict__ part) {
    const int tid = blockIdx.x * CS_THREADS + threadIdx.x;
    const int stride = CS_BLOCKS * CS_THREADS;
    float4 a = make_float4(0.f, 0.f, 0.f, 0.f);
    for (int idx = tid; idx < NFLOAT4; idx += stride) {
        const float4 v = emb4[idx];
        a.x += v.x; a.y += v.y; a.z += v.z; a.w += v.w;
    }
    // lane l and l^32 hold the same columns -> fold wave to 32 lanes
    a.x += __shfl_xor(a.x, 32);
    a.y += __shfl_xor(a.y, 32);
    a.z += __shfl_xor(a.z, 32);
    a.w += __shfl_xor(a.w, 32);

    __shared__ float sm[4][DIM];          // one row per wave
    const int wid  = threadIdx.x >> 6;
    const int lane = threadIdx.x & 63;
    const int col  = (threadIdx.x * 4) & 127;
    if (lane < 32) {
        sm[wid][col + 0] = a.x;
        sm[wid][col + 1] = a.y;
        sm[wid][col + 2] = a.z;
        sm[wid][col + 3] = a.w;
    }
    __syncthreads();
    if (threadIdx.x < DIM) {
        part[blockIdx.x * DIM + threadIdx.x] =
            sm[0][threadIdx.x] + sm[1][threadIdx.x] +
            sm[2][threadIdx.x] + sm[3][threadIdx.x];
    }
}

// ---------------- Kernel B: fold partials -> S[128] ----------------
__global__ void colsum_reduce(const float* __restrict__ part,
                              float* __restrict__ S) {
    __shared__ float sm[8][DIM];
    const int t = threadIdx.x;            // 1024 threads
    const int col = t & 127, g = t >> 7;  // 8 groups of 128
    float s = 0.f;
    for (int b = g; b < CS_BLOCKS; b += 8) s += part[b * DIM + col];
    sm[g][col] = s;
    __syncthreads();
    if (t < DIM) {
        float tot = 0.f;
        #pragma unroll
        for (int g2 = 0; g2 < 8; ++g2) tot += sm[g2][t];
        S[t] = tot;
    }
}

// ---------------- Kernel C: per-pair cost, per-block partial sums -----------
__global__ void pair_kernel(const float* __restrict__ emb,
                            const int* __restrict__ iv,
                            const int* __restrict__ jv,
                            const float* __restrict__ S,
                            float* __restrict__ blockpart) {
    const int lane = threadIdx.x & 63;
    const int wid  = threadIdx.x >> 6;
    const int wavesPerBlock = blockDim.x >> 6;
    const int gw = blockIdx.x * wavesPerBlock + wid;
    const int nw = gridDim.x * wavesPerBlock;

    const float2 sv = reinterpret_cast<const float2*>(S)[lane];

    float acc = 0.f;
    for (int p = gw; p < NPAIRS; p += nw) {
        const int i = iv[p];
        const int j = jv[p];
        const float2 ei = reinterpret_cast<const float2*>(emb + (size_t)i * DIM)[lane];
        const float2 ej = reinterpret_cast<const float2*>(emb + (size_t)j * DIM)[lane];
        float d = ei.x * ej.x + ei.y * ej.y;   // e_i . e_j  (partial)
        float n = ei.x * sv.x + ei.y * sv.y;   // e_i . S    (partial)
        #pragma unroll
        for (int off = 32; off > 0; off >>= 1) {
            d += __shfl_xor(d, off);
            n += __shfl_xor(n, off);
        }
        const float cost = -logf(expf(d - n) + 1e-8f);
        if (lane == 0) acc += cost;
    }

    __shared__ float ls[8];
    if (lane == 0) ls[wid] = acc;
    __syncthreads();
    if (threadIdx.x == 0) {
        float s = 0.f;
        for (int w = 0; w < wavesPerBlock; ++w) s += ls[w];
        blockpart[blockIdx.x] = s;
    }
}

// ---------------- Kernel D: final reduce -> mean ----------------
__global__ void final_reduce(const float* __restrict__ blockpart,
                             float* __restrict__ out) {
    const int t = threadIdx.x;            // 256 threads
    float s = 0.f;
    for (int idx = t; idx < PAIR_BLOCKS; idx += blockDim.x) s += blockpart[idx];
    #pragma unroll
    for (int off = 32; off > 0; off >>= 1) s += __shfl_xor(s, off);
    __shared__ float ls[4];
    if ((t & 63) == 0) ls[t >> 6] = s;
    __syncthreads();
    if (t == 0) {
        float tot = ls[0] + ls[1] + ls[2] + ls[3];
        out[0] = tot / (float)NPAIRS;
    }
}

extern "C" void kernel_launch(void* const* d_in, const int* in_sizes, int n_in,
                              void* d_out, int out_size, void* d_ws, size_t ws_size,
                              hipStream_t stream) {
    const float* emb = (const float*)d_in[0];
    const int*   iv  = (const int*)d_in[1];
    const int*   jv  = (const int*)d_in[2];
    float* out = (float*)d_out;

    float* ws    = (float*)d_ws;
    float* part  = ws;                              // CS_BLOCKS*128 floats
    float* S     = part + CS_BLOCKS * DIM;          // 128 floats
    float* bpart = S + DIM;                         // PAIR_BLOCKS floats

    hipLaunchKernelGGL(colsum_partial, dim3(CS_BLOCKS), dim3(CS_THREADS), 0, stream,
                       (const float4*)emb, part);
    hipLaunchKernelGGL(colsum_reduce, dim3(1), dim3(1024), 0, stream,
                       part, S);
    hipLaunchKernelGGL(pair_kernel, dim3(PAIR_BLOCKS), dim3(256), 0, stream,
                       emb, iv, jv, S, bpart);
    hipLaunchKernelGGL(final_reduce, dim3(1), dim3(256), 0, stream,
                       bpart, out);
}